// Round 1
// baseline (794.763 us; speedup 1.0000x reference)
//
#include <hip/hip_runtime.h>

// ---------------------------------------------------------------------------
// GCN 2-layer forward on MI355X.
// out1 = relu( smooth( X@W1 + b1 ) )          [N,64]
// out2 = smooth( relu_out @ W2 + b2 )          [N,40]
// smooth(H) = scatter_add over edges (both dirs) with dis[s]*dis[d] weights
//             + H * dis^2 (self loop), dis = rsqrt(1 + in_deg + out_deg).
// ---------------------------------------------------------------------------

__global__ void k_deg_init(float* __restrict__ deg, int N) {
    int i = blockIdx.x * blockDim.x + threadIdx.x;
    if (i < N) deg[i] = 1.0f;
}

__global__ void k_deg_accum(const int* __restrict__ src, const int* __restrict__ dst,
                            float* __restrict__ deg, int E) {
    int e = blockIdx.x * blockDim.x + threadIdx.x;
    if (e < E) {
        atomicAdd(&deg[src[e]], 1.0f);
        atomicAdd(&deg[dst[e]], 1.0f);
    }
}

__global__ void k_rsqrt(float* __restrict__ deg, int N) {
    int i = blockIdx.x * blockDim.x + threadIdx.x;
    if (i < N) deg[i] = 1.0f / sqrtf(deg[i]);
}

// h[N][64] = X[N][128] @ W1[128][64] + b1.  Block = 256 thr = 4 waves.
// Each wave: one group of 4 rows, lane = col. W1 staged in LDS (32 KB).
__global__ __launch_bounds__(256) void k_gemm1(const float* __restrict__ X,
                                               const float* __restrict__ W1,
                                               const float* __restrict__ b1,
                                               float* __restrict__ h, int N) {
    __shared__ float sW[128 * 64];
    for (int i = threadIdx.x; i < 128 * 64; i += 256) sW[i] = W1[i];
    __syncthreads();

    const int col = threadIdx.x & 63;
    const int r0  = blockIdx.x * 16 + (threadIdx.x >> 6) * 4;
    if (r0 >= N) return;
    const float b = b1[col];

    if (r0 + 3 < N) {
        const float4* x0 = (const float4*)(X + (size_t)r0 * 128);
        float acc0 = 0.f, acc1 = 0.f, acc2 = 0.f, acc3 = 0.f;
        #pragma unroll
        for (int k4 = 0; k4 < 32; ++k4) {
            float4 a0 = x0[k4];
            float4 a1 = x0[32 + k4];
            float4 a2 = x0[64 + k4];
            float4 a3 = x0[96 + k4];
            const float* w = &sW[k4 * 4 * 64 + col];
            float w0 = w[0], w1 = w[64], w2 = w[128], w3 = w[192];
            acc0 += a0.x * w0 + a0.y * w1 + a0.z * w2 + a0.w * w3;
            acc1 += a1.x * w0 + a1.y * w1 + a1.z * w2 + a1.w * w3;
            acc2 += a2.x * w0 + a2.y * w1 + a2.z * w2 + a2.w * w3;
            acc3 += a3.x * w0 + a3.y * w1 + a3.z * w2 + a3.w * w3;
        }
        h[(size_t)(r0 + 0) * 64 + col] = acc0 + b;
        h[(size_t)(r0 + 1) * 64 + col] = acc1 + b;
        h[(size_t)(r0 + 2) * 64 + col] = acc2 + b;
        h[(size_t)(r0 + 3) * 64 + col] = acc3 + b;
    } else {
        for (int j = 0; j < 4 && r0 + j < N; ++j) {
            const float* xr = X + (size_t)(r0 + j) * 128;
            float acc = 0.f;
            for (int k = 0; k < 128; ++k) acc += xr[k] * sW[k * 64 + col];
            h[(size_t)(r0 + j) * 64 + col] = acc + b;
        }
    }
}

// Self-loop init: out[i][c] = h[i][c] * dis[i]^2   (64-wide)
__global__ void k_self64(const float* __restrict__ h, const float* __restrict__ dis,
                         float* __restrict__ out, int n64) {
    int t = blockIdx.x * blockDim.x + threadIdx.x;
    if (t >= n64) return;
    float w = dis[t >> 6];
    out[t] = h[t] * w * w;
}

// Edge scatter, 64 channels: 64 lanes per edge (edge is wave-uniform).
__global__ void k_smooth64(const int* __restrict__ src, const int* __restrict__ dst,
                           const float* __restrict__ dis, const float* __restrict__ h,
                           float* __restrict__ out, int E) {
    int t = blockIdx.x * blockDim.x + threadIdx.x;
    int e = t >> 6;
    int c = t & 63;
    if (e >= E) return;
    int s = src[e], d = dst[e];
    float norm = dis[s] * dis[d];
    atomicAdd(&out[(size_t)d * 64 + c], h[(size_t)s * 64 + c] * norm);
    atomicAdd(&out[(size_t)s * 64 + c], h[(size_t)d * 64 + c] * norm);
}

__global__ void k_relu(float* __restrict__ x, int n) {
    int t = blockIdx.x * blockDim.x + threadIdx.x;
    if (t < n) x[t] = fmaxf(x[t], 0.0f);
}

// h2[N][40] = A[N][64] @ W2[64][40] + b2. Flat: one thread per output elem.
__global__ void k_gemm2(const float* __restrict__ A, const float* __restrict__ W2,
                        const float* __restrict__ b2, float* __restrict__ h2, int n40) {
    int t = blockIdx.x * blockDim.x + threadIdx.x;
    if (t >= n40) return;
    int row = t / 40;
    int col = t - row * 40;
    const float* a = A + (size_t)row * 64;
    float acc = b2[col];
    #pragma unroll
    for (int k = 0; k < 64; ++k) acc += a[k] * W2[k * 40 + col];
    h2[t] = acc;
}

// Self-loop init, 40-wide.
__global__ void k_self40(const float* __restrict__ h2, const float* __restrict__ dis,
                         float* __restrict__ out, int n40) {
    int t = blockIdx.x * blockDim.x + threadIdx.x;
    if (t >= n40) return;
    int i = t / 40;
    float w = dis[i];
    out[t] = h2[t] * w * w;
}

// Edge scatter, 40 channels: flat over E*40.
__global__ void k_smooth40(const int* __restrict__ src, const int* __restrict__ dst,
                           const float* __restrict__ dis, const float* __restrict__ h2,
                           float* __restrict__ out, int E) {
    int t = blockIdx.x * blockDim.x + threadIdx.x;
    if (t >= E * 40) return;
    int e = t / 40;
    int c = t - e * 40;
    int s = src[e], d = dst[e];
    float norm = dis[s] * dis[d];
    atomicAdd(&out[(size_t)d * 40 + c], h2[(size_t)s * 40 + c] * norm);
    atomicAdd(&out[(size_t)s * 40 + c], h2[(size_t)d * 40 + c] * norm);
}

extern "C" void kernel_launch(void* const* d_in, const int* in_sizes, int n_in,
                              void* d_out, int out_size, void* d_ws, size_t ws_size,
                              hipStream_t stream) {
    const float* X  = (const float*)d_in[0];
    const float* W1 = (const float*)d_in[1];
    const float* b1 = (const float*)d_in[2];
    const float* W2 = (const float*)d_in[3];
    const float* b2 = (const float*)d_in[4];
    const int*   ei = (const int*)d_in[5];

    const int Chid = in_sizes[2];            // 64
    const int Cin  = in_sizes[1] / Chid;     // 128
    const int N    = in_sizes[0] / Cin;      // 50000
    const int E    = in_sizes[5] / 2;        // 800000

    const int* src = ei;
    const int* dst = ei + E;

    // workspace layout
    float* dis = (float*)d_ws;                                   // N floats
    size_t off = ((size_t)N * 4 + 255) & ~(size_t)255;
    float* h   = (float*)((char*)d_ws + off);                    // N*64 floats
    float* h2  = h + (size_t)N * 64;                             // N*40 floats

    float* out1 = (float*)d_out;                                 // N*64
    float* out2 = out1 + (size_t)N * 64;                         // N*40

    const int T = 256;

    k_deg_init<<<(N + T - 1) / T, T, 0, stream>>>(dis, N);
    k_deg_accum<<<(E + T - 1) / T, T, 0, stream>>>(src, dst, dis, E);
    k_rsqrt<<<(N + T - 1) / T, T, 0, stream>>>(dis, N);

    k_gemm1<<<(N + 15) / 16, T, 0, stream>>>(X, W1, b1, h, N);

    int n64 = N * 64;
    k_self64<<<(n64 + T - 1) / T, T, 0, stream>>>(h, dis, out1, n64);
    long long t64 = (long long)E * 64;
    k_smooth64<<<(int)((t64 + T - 1) / T), T, 0, stream>>>(src, dst, dis, h, out1, E);
    k_relu<<<(n64 + T - 1) / T, T, 0, stream>>>(out1, n64);

    int n40 = N * 40;
    k_gemm2<<<(n40 + T - 1) / T, T, 0, stream>>>(out1, W2, b2, h2, n40);
    k_self40<<<(n40 + T - 1) / T, T, 0, stream>>>(h2, dis, out2, n40);
    long long t40 = (long long)E * 40;
    k_smooth40<<<(int)((t40 + T - 1) / T), T, 0, stream>>>(src, dst, dis, h2, out2, E);
}

// Round 2
// 431.405 us; speedup vs baseline: 1.8423x; 1.8423x over previous
//
#include <hip/hip_runtime.h>

// ---------------------------------------------------------------------------
// GCN 2-layer forward, gather-based (atomic-free feature smoothing).
//   dis = rsqrt(1 + deg_src + deg_dst)
//   hs  = (X@W1 + b1) * dis[i]           (row-scaled)
//   out1 = relu( dis[i] * (hs[i] + sum_{j in adj(i)} hs[j]) )
//   h2s = (out1@W2 + b2) * dis[i]
//   out2 = dis[i] * (h2s[i] + sum_j h2s[j])
// CSR adjacency built per call: count -> scan -> fill (int atomics only).
// ---------------------------------------------------------------------------

__global__ void k_zero_i32(int* __restrict__ p, int n) {
    int i = blockIdx.x * blockDim.x + threadIdx.x;
    if (i < n) p[i] = 0;
}

__global__ void k_count(const int* __restrict__ src, const int* __restrict__ dst,
                        int* __restrict__ cnt, int E) {
    int e = blockIdx.x * blockDim.x + threadIdx.x;
    if (e < E) {
        atomicAdd(&cnt[src[e]], 1);
        atomicAdd(&cnt[dst[e]], 1);
    }
}

__global__ __launch_bounds__(256) void k_block_sum(const int* __restrict__ cnt,
                                                   int* __restrict__ bsum, int N) {
    __shared__ int s[256];
    int i = blockIdx.x * 256 + threadIdx.x;
    s[threadIdx.x] = (i < N) ? cnt[i] : 0;
    __syncthreads();
    for (int d = 128; d > 0; d >>= 1) {
        if (threadIdx.x < d) s[threadIdx.x] += s[threadIdx.x + d];
        __syncthreads();
    }
    if (threadIdx.x == 0) bsum[blockIdx.x] = s[0];
}

__global__ void k_scan_bsum(int* __restrict__ bsum, int nb) {
    if (threadIdx.x == 0 && blockIdx.x == 0) {
        int run = 0;
        for (int b = 0; b < nb; ++b) { int v = bsum[b]; bsum[b] = run; run += v; }
    }
}

// Intra-block exclusive scan + add block base; also emit cursor copy and dis.
__global__ __launch_bounds__(256) void k_scan_block(const int* __restrict__ cnt,
                                                    const int* __restrict__ bscan,
                                                    int* __restrict__ offs,
                                                    int* __restrict__ cursor,
                                                    float* __restrict__ dis, int N) {
    __shared__ int s[2][256];
    int t = threadIdx.x;
    int i = blockIdx.x * 256 + t;
    int v = (i < N) ? cnt[i] : 0;
    s[0][t] = v;
    __syncthreads();
    int pin = 0;
    for (int d = 1; d < 256; d <<= 1) {
        int pout = pin ^ 1;
        int val = s[pin][t];
        if (t >= d) val += s[pin][t - d];
        s[pout][t] = val;
        __syncthreads();
        pin = pout;
    }
    if (i < N) {
        int excl = s[pin][t] - v + bscan[blockIdx.x];
        offs[i] = excl;
        cursor[i] = excl;
        dis[i] = rsqrtf(1.0f + (float)v);
    }
}

__global__ void k_fill(const int* __restrict__ src, const int* __restrict__ dst,
                       int* __restrict__ cursor, int* __restrict__ adj, int E) {
    int e = blockIdx.x * blockDim.x + threadIdx.x;
    if (e >= E) return;
    int s = src[e], d = dst[e];
    int p = atomicAdd(&cursor[s], 1);
    adj[p] = d;
    int q = atomicAdd(&cursor[d], 1);
    adj[q] = s;
}

// hs[N][64] = (X[N][128] @ W1[128][64] + b1) * dis[row]
__global__ __launch_bounds__(256) void k_gemm1(const float* __restrict__ X,
                                               const float* __restrict__ W1,
                                               const float* __restrict__ b1,
                                               const float* __restrict__ dis,
                                               float* __restrict__ hs, int N) {
    __shared__ float sW[128 * 64];
    for (int i = threadIdx.x; i < 128 * 64; i += 256) sW[i] = W1[i];
    __syncthreads();

    const int col = threadIdx.x & 63;
    const int r0  = blockIdx.x * 16 + (threadIdx.x >> 6) * 4;
    if (r0 >= N) return;
    const float b = b1[col];

    if (r0 + 3 < N) {
        const float4* x0 = (const float4*)(X + (size_t)r0 * 128);
        float acc0 = 0.f, acc1 = 0.f, acc2 = 0.f, acc3 = 0.f;
        #pragma unroll
        for (int k4 = 0; k4 < 32; ++k4) {
            float4 a0 = x0[k4];
            float4 a1 = x0[32 + k4];
            float4 a2 = x0[64 + k4];
            float4 a3 = x0[96 + k4];
            const float* w = &sW[k4 * 4 * 64 + col];
            float w0 = w[0], w1 = w[64], w2 = w[128], w3 = w[192];
            acc0 += a0.x * w0 + a0.y * w1 + a0.z * w2 + a0.w * w3;
            acc1 += a1.x * w0 + a1.y * w1 + a1.z * w2 + a1.w * w3;
            acc2 += a2.x * w0 + a2.y * w1 + a2.z * w2 + a2.w * w3;
            acc3 += a3.x * w0 + a3.y * w1 + a3.z * w2 + a3.w * w3;
        }
        hs[(size_t)(r0 + 0) * 64 + col] = (acc0 + b) * dis[r0 + 0];
        hs[(size_t)(r0 + 1) * 64 + col] = (acc1 + b) * dis[r0 + 1];
        hs[(size_t)(r0 + 2) * 64 + col] = (acc2 + b) * dis[r0 + 2];
        hs[(size_t)(r0 + 3) * 64 + col] = (acc3 + b) * dis[r0 + 3];
    } else {
        for (int j = 0; j < 4 && r0 + j < N; ++j) {
            const float* xr = X + (size_t)(r0 + j) * 128;
            float acc = 0.f;
            for (int k = 0; k < 128; ++k) acc += xr[k] * sW[k * 64 + col];
            hs[(size_t)(r0 + j) * 64 + col] = (acc + b) * dis[r0 + j];
        }
    }
}

// out1[i][c] = relu( dis[i] * (hs[i][c] + sum_j hs[j][c]) ); wave per node.
__global__ __launch_bounds__(256) void k_gather64(const float* __restrict__ hs,
                                                  const int* __restrict__ adj,
                                                  const int* __restrict__ offs,
                                                  const int* __restrict__ cnt,
                                                  const float* __restrict__ dis,
                                                  float* __restrict__ out, int N) {
    int node = (blockIdx.x * 256 + threadIdx.x) >> 6;
    int c = threadIdx.x & 63;
    if (node >= N) return;
    int off = offs[node];
    int n = cnt[node];
    float acc = hs[(size_t)node * 64 + c];
    int k = 0;
    for (; k + 4 <= n; k += 4) {
        int j0 = adj[off + k + 0];
        int j1 = adj[off + k + 1];
        int j2 = adj[off + k + 2];
        int j3 = adj[off + k + 3];
        float v0 = hs[(size_t)j0 * 64 + c];
        float v1 = hs[(size_t)j1 * 64 + c];
        float v2 = hs[(size_t)j2 * 64 + c];
        float v3 = hs[(size_t)j3 * 64 + c];
        acc += v0 + v1 + v2 + v3;
    }
    for (; k < n; ++k) {
        int j = adj[off + k];
        acc += hs[(size_t)j * 64 + c];
    }
    out[(size_t)node * 64 + c] = fmaxf(dis[node] * acc, 0.0f);
}

// h2s[N][40] = (out1[N][64] @ W2[64][40] + b2) * dis[row]
__global__ __launch_bounds__(256) void k_gemm2(const float* __restrict__ A,
                                               const float* __restrict__ W2,
                                               const float* __restrict__ b2,
                                               const float* __restrict__ dis,
                                               float* __restrict__ h2s, int n40) {
    __shared__ float sW[64 * 40];
    __shared__ float sb[40];
    for (int i = threadIdx.x; i < 64 * 40; i += 256) sW[i] = W2[i];
    if (threadIdx.x < 40) sb[threadIdx.x] = b2[threadIdx.x];
    __syncthreads();
    int t = blockIdx.x * 256 + threadIdx.x;
    if (t >= n40) return;
    int row = t / 40;
    int col = t - row * 40;
    const float4* a = (const float4*)(A + (size_t)row * 64);
    float acc = sb[col];
    #pragma unroll
    for (int k4 = 0; k4 < 16; ++k4) {
        float4 v = a[k4];
        const float* w = &sW[k4 * 4 * 40 + col];
        acc += v.x * w[0] + v.y * w[40] + v.z * w[80] + v.w * w[120];
    }
    h2s[t] = acc * dis[row];
}

// out2[i][c] = dis[i] * (h2s[i][c] + sum_j h2s[j][c]); wave per node, 40 lanes.
__global__ __launch_bounds__(256) void k_gather40(const float* __restrict__ h2s,
                                                  const int* __restrict__ adj,
                                                  const int* __restrict__ offs,
                                                  const int* __restrict__ cnt,
                                                  const float* __restrict__ dis,
                                                  float* __restrict__ out, int N) {
    int node = (blockIdx.x * 256 + threadIdx.x) >> 6;
    int c = threadIdx.x & 63;
    if (node >= N || c >= 40) return;
    int off = offs[node];
    int n = cnt[node];
    float acc = h2s[(size_t)node * 40 + c];
    int k = 0;
    for (; k + 4 <= n; k += 4) {
        int j0 = adj[off + k + 0];
        int j1 = adj[off + k + 1];
        int j2 = adj[off + k + 2];
        int j3 = adj[off + k + 3];
        float v0 = h2s[(size_t)j0 * 40 + c];
        float v1 = h2s[(size_t)j1 * 40 + c];
        float v2 = h2s[(size_t)j2 * 40 + c];
        float v3 = h2s[(size_t)j3 * 40 + c];
        acc += v0 + v1 + v2 + v3;
    }
    for (; k < n; ++k) {
        int j = adj[off + k];
        acc += h2s[(size_t)j * 40 + c];
    }
    out[(size_t)node * 40 + c] = dis[node] * acc;
}

extern "C" void kernel_launch(void* const* d_in, const int* in_sizes, int n_in,
                              void* d_out, int out_size, void* d_ws, size_t ws_size,
                              hipStream_t stream) {
    const float* X  = (const float*)d_in[0];
    const float* W1 = (const float*)d_in[1];
    const float* b1 = (const float*)d_in[2];
    const float* W2 = (const float*)d_in[3];
    const float* b2 = (const float*)d_in[4];
    const int*   ei = (const int*)d_in[5];

    const int Chid = in_sizes[2];            // 64
    const int Cin  = in_sizes[1] / Chid;     // 128
    const int N    = in_sizes[0] / Cin;      // 50000
    const int E    = in_sizes[5] / 2;        // 800000

    const int* src = ei;
    const int* dst = ei + E;

    // ---- workspace layout (256B aligned chunks) ----
    auto align256 = [](size_t x) { return (x + 255) & ~(size_t)255; };
    char* p = (char*)d_ws;
    int*   cnt    = (int*)p;   p += align256((size_t)N * 4);
    int*   offs   = (int*)p;   p += align256((size_t)N * 4);
    int*   cursor = (int*)p;   p += align256((size_t)N * 4);
    int*   bsum   = (int*)p;   p += align256(4096);
    float* dis    = (float*)p; p += align256((size_t)N * 4);
    int*   adj    = (int*)p;   p += align256((size_t)2 * E * 4);
    float* hs     = (float*)p;                    // N*64 floats
    float* h2s    = hs;                           // reuse after out1 is done

    float* out1 = (float*)d_out;                  // N*64
    float* out2 = out1 + (size_t)N * 64;          // N*40

    const int T = 256;
    const int NB = (N + T - 1) / T;

    k_zero_i32<<<NB, T, 0, stream>>>(cnt, N);
    k_count<<<(E + T - 1) / T, T, 0, stream>>>(src, dst, cnt, E);
    k_block_sum<<<NB, T, 0, stream>>>(cnt, bsum, N);
    k_scan_bsum<<<1, 64, 0, stream>>>(bsum, NB);
    k_scan_block<<<NB, T, 0, stream>>>(cnt, bsum, offs, cursor, dis, N);
    k_fill<<<(E + T - 1) / T, T, 0, stream>>>(src, dst, cursor, adj, E);

    k_gemm1<<<(N + 15) / 16, T, 0, stream>>>(X, W1, b1, dis, hs, N);
    k_gather64<<<(N + 3) / 4, T, 0, stream>>>(hs, adj, offs, cnt, dis, out1, N);

    int n40 = N * 40;
    k_gemm2<<<(n40 + T - 1) / T, T, 0, stream>>>(out1, W2, b2, dis, h2s, n40);
    k_gather40<<<(N + 3) / 4, T, 0, stream>>>(h2s, adj, offs, cnt, dis, out2, N);
}